// Round 1
// baseline (1001.445 us; speedup 1.0000x reference)
//
#include <hip/hip_runtime.h>
#include <hip/hip_cooperative_groups.h>
#include <stdint.h>

namespace cg = cooperative_groups;

typedef _Float16 half8 __attribute__((ext_vector_type(8)));
typedef float f32x4 __attribute__((ext_vector_type(4)));

typedef const __attribute__((address_space(1))) void* gptr_t;
typedef __attribute__((address_space(3))) void* lptr_t;
static __device__ __forceinline__ void gll16(const void* g, void* l) {
  __builtin_amdgcn_global_load_lds((gptr_t)(unsigned long long)g,
                                   (lptr_t)(unsigned int)(unsigned long long)l,
                                   16, 0, 0);
}

// ---------------- M-build: M[l] = [eenc_w @ nn1_w[l]; eenc_b @ nn1_w[l] + nn1_b[l]] ----------------
__global__ __launch_bounds__(256)
void k_M(const float* __restrict__ eenc_w, const float* __restrict__ eenc_b,
         const float* __restrict__ nn1_w, const float* __restrict__ nn1_b,
         float* __restrict__ Mbuf) {
  int l = blockIdx.x, t = threadIdx.x;
  if (t >= 192) return;
  float a0 = 0.f, a1 = 0.f, a2 = 0.f, a3 = 0.f, a4 = 0.f;
  const float* nw = nn1_w + (size_t)l * 36864 + t;
  for (int k = 0; k < 192; ++k) {
    float nv = nw[(size_t)k * 192];
    a0 += eenc_w[k] * nv;
    a1 += eenc_w[192 + k] * nv;
    a2 += eenc_w[384 + k] * nv;
    a3 += eenc_w[576 + k] * nv;
    a4 += eenc_b[k] * nv;
  }
  float* Ml = Mbuf + l * 960;
  Ml[t] = a0; Ml[192 + t] = a1; Ml[384 + t] = a2; Ml[576 + t] = a3;
  Ml[768 + t] = a4 + nn1_b[l * 192 + t];
}

// ---------------- P = M @ W2 (the 113MB stream) + Cheb chain + CSR build riding along ----------------
// grid (37,4,2): x<36 -> pb workers; (36,0,0) -> Cheb chain; (36,1,0) -> CSR by dst; rest exit.
__global__ __launch_bounds__(256)
void k_pb(const float* __restrict__ nn2_w, const float* __restrict__ Mbuf,
          float* __restrict__ Ppart,
          const float* __restrict__ x, const int* __restrict__ ei,
          float* __restrict__ Tx, int* __restrict__ rowptr, int* __restrict__ eord) {
  __shared__ __align__(16) float smem[15360];  // 60KB, unioned between the two helper blocks
  if (blockIdx.x == 36) {
    int t = threadIdx.x;
    if (blockIdx.y == 0 && blockIdx.z == 0) {
      // ---- Chebyshev chain (self-contained; hides under the pb stream) ----
      float* deg = smem;            // 1024
      float* wn  = smem + 1024;     // 2048
      float* T0  = smem + 3072;     // 4096
      float* T1  = smem + 7168;     // 4096
      float* yv  = smem + 11264;    // 4096
      for (int i = t; i < 1024; i += 256) deg[i] = 0.f;
      __syncthreads();
      for (int e = t; e < 2048; e += 256) atomicAdd(&deg[ei[e]], 1.f);
      __syncthreads();
      for (int e = t; e < 2048; e += 256) {
        int s = ei[e], d = ei[2048 + e];
        float ds = deg[s], dd = deg[d];
        float a = ds > 0.f ? 1.f / sqrtf(fmaxf(ds, 1.f)) : 0.f;
        float b = dd > 0.f ? 1.f / sqrtf(fmaxf(dd, 1.f)) : 0.f;
        wn[e] = -a * b;
      }
      for (int i = t; i < 1024; i += 256) {
        float4 xv = ((const float4*)x)[i];
        ((float4*)T0)[i] = xv;
        ((float4*)Tx)[i] = xv;
      }
      __syncthreads();
      float* cur = T0; float* nxt = T1;
      for (int rec = 0; rec < 4; ++rec) {
        for (int i = t; i < 1024; i += 256) ((float4*)yv)[i] = make_float4(0.f, 0.f, 0.f, 0.f);
        __syncthreads();
        for (int e = t; e < 2048; e += 256) {
          int s = ei[e], d = ei[2048 + e];
          float wv = wn[e];
#pragma unroll
          for (int c = 0; c < 4; ++c) atomicAdd(&yv[d * 4 + c], wv * cur[s * 4 + c]);
        }
        __syncthreads();
        float a = (rec == 0) ? 1.f : 2.f;
        for (int i = t; i < 1024; i += 256) {
          float4 y4 = ((float4*)yv)[i];
          float4 p4 = ((float4*)nxt)[i];
          float4 n4;
          n4.x = a * y4.x - (rec ? p4.x : 0.f);
          n4.y = a * y4.y - (rec ? p4.y : 0.f);
          n4.z = a * y4.z - (rec ? p4.z : 0.f);
          n4.w = a * y4.w - (rec ? p4.w : 0.f);
          ((float4*)nxt)[i] = n4;
          ((float4*)(Tx + (rec + 1) * 4096))[i] = n4;
        }
        __syncthreads();
        float* tmp = cur; cur = nxt; nxt = tmp;
      }
    } else if (blockIdx.y == 1 && blockIdx.z == 0) {
      // ---- CSR by dst: rowptr[1025], eord[2048] ----
      int* cnt = (int*)smem;
      int* rp  = (int*)(smem + 1024);
      int* wtot = (int*)(smem + 2048);
      int lane = t & 63, wv = t >> 6;
      for (int i = t; i < 1024; i += 256) cnt[i] = 0;
      __syncthreads();
      for (int e = t; e < 2048; e += 256) atomicAdd(&cnt[ei[2048 + e]], 1);
      __syncthreads();
      int c0 = cnt[t * 4], c1 = cnt[t * 4 + 1], c2 = cnt[t * 4 + 2], c3 = cnt[t * 4 + 3];
      int s = c0 + c1 + c2 + c3;
      int inc = s;
#pragma unroll
      for (int off = 1; off < 64; off <<= 1) {
        int u = __shfl_up(inc, off);
        if (lane >= off) inc += u;
      }
      if (lane == 63) wtot[wv] = inc;
      __syncthreads();
      int woff = 0;
#pragma unroll
      for (int j = 0; j < 4; ++j) if (j < wv) woff += wtot[j];
      int excl = woff + inc - s;
      int4 r4; r4.x = excl; r4.y = excl + c0; r4.z = excl + c0 + c1; r4.w = excl + c0 + c1 + c2;
      *(int4*)(rowptr + t * 4) = r4;
      if (t == 0) rowptr[1024] = 2048;
      rp[t * 4] = r4.x; rp[t * 4 + 1] = r4.y; rp[t * 4 + 2] = r4.z; rp[t * 4 + 3] = r4.w;
      __syncthreads();
      for (int e = t; e < 2048; e += 256) {
        int d = ei[2048 + e];
        int slot = atomicAdd(&rp[d], 1);
        eord[slot] = e;
      }
    }
    return;
  }
  // ---- pb worker: k-split partials of P = M @ W2 ----
  int l = blockIdx.y, kc = blockIdx.z;
  int col = blockIdx.x * 1024 + threadIdx.x * 4;
  const float* W = nn2_w + (size_t)l * 7077888 + col;
  const float* Mp = Mbuf + l * 960 + kc * 96;
  f32x4 acc0 = {}, acc1 = {}, acc2 = {}, acc3 = {}, acc4 = {};
  const size_t rs = 36864;
  const float* Wk = W + (size_t)(kc * 96) * rs;
#pragma unroll 8
  for (int k = 0; k < 96; ++k) {
    f32x4 wv = *(const f32x4*)(Wk + (size_t)k * rs);
    acc0 += wv * Mp[k];
    acc1 += wv * Mp[192 + k];
    acc2 += wv * Mp[384 + k];
    acc3 += wv * Mp[576 + k];
    acc4 += wv * Mp[768 + k];
  }
  float* Pp = Ppart + ((size_t)(kc * 4 + l) * 5) * 36864 + col;
  *(f32x4*)(Pp) = acc0;
  *(f32x4*)(Pp + 36864) = acc1;
  *(f32x4*)(Pp + 2 * 36864) = acc2;
  *(f32x4*)(Pp + 3 * 36864) = acc3;
  *(f32x4*)(Pp + 4 * 36864) = acc4;
}

// ---------------- cooperative: stageB+cheb_out, 4x(Y-GEMM -> gather/node/LN), final ----------------
__global__ __launch_bounds__(256)
void k_all(const float* __restrict__ Ppart, const float* __restrict__ nn2_b,
           const float* __restrict__ root_w, _Float16* __restrict__ Btl,
           const float* __restrict__ Tx, const float* __restrict__ cheb_w,
           const float* __restrict__ cheb_b, float* __restrict__ h0,
           const int* __restrict__ ei, const float* __restrict__ eattr,
           const int* __restrict__ rowptr, const int* __restrict__ eord,
           const float* __restrict__ conv_b, const float* __restrict__ ln_g,
           const float* __restrict__ ln_b, const float* __restrict__ out_w,
           const float* __restrict__ out_b,
           float* __restrict__ Y, float* __restrict__ hA, float* __restrict__ hB,
           float* __restrict__ zA, float* __restrict__ zB, float* __restrict__ outp) {
  cg::grid_group grid = cg::this_grid();
  __shared__ __align__(16) _Float16 sm[24576];  // Al: 24 ck x 64 rows x 8 | Bl: 2 x (4 ck x 192 x 8)
  _Float16* Al = sm;
  _Float16* Bl = sm + 12288;
  int b = blockIdx.x, t = threadIdx.x;
  int w = t >> 6, lane = t & 63, l15 = lane & 15, q4 = lane >> 4;
  int n = b * 4 + w;  // node owned by this wave (256 blocks x 4 waves = 1024 nodes)
  int o0 = lane, o1 = lane + 64, o2 = lane + 128;

  // ---- P0: stageB (blocks 0..95) ----
  if (b < 96) {
    int ck = b % 24, l = b / 24;
    _Float16* out = Btl + (size_t)l * 221184 + ck * 9216;
#pragma unroll
    for (int it = 0; it < 5; ++it) {
      int nn = it * 256 + t;
      if (nn >= 1152) break;
      union { _Float16 h[8]; uint4 v; } u;
      if (nn < 960) {
        int c = nn / 192, o = nn - c * 192;
        const float* P0 = Ppart + ((size_t)(0 * 4 + l) * 5 + c) * 36864;
        const float* P1 = Ppart + ((size_t)(1 * 4 + l) * 5 + c) * 36864;
#pragma unroll
        for (int j = 0; j < 8; ++j) {
          int io = (ck * 8 + j) * 192 + o;
          float val = P0[io] + P1[io];
          if (c == 4) val += nn2_b[(size_t)l * 36864 + io];
          u.h[j] = (_Float16)val;
        }
      } else {
        int o = nn - 960;
#pragma unroll
        for (int j = 0; j < 8; ++j)
          u.h[j] = (_Float16)root_w[(size_t)l * 36864 + (ck * 8 + j) * 192 + o];
      }
      *(uint4*)(out + (size_t)nn * 8) = u.v;
    }
  }
  // ---- P0: cheb_out, wave-per-node (all blocks) ----
  {
    float a0 = cheb_b[o0], a1 = cheb_b[o1], a2 = cheb_b[o2];
#pragma unroll
    for (int k = 0; k < 5; ++k)
#pragma unroll
      for (int c = 0; c < 4; ++c) {
        float tv = Tx[k * 4096 + n * 4 + c];
        const float* cwp = cheb_w + (k * 4 + c) * 192;
        a0 += tv * cwp[o0]; a1 += tv * cwp[o1]; a2 += tv * cwp[o2];
      }
    h0[n * 192 + o0] = a0; h0[n * 192 + o1] = a1; h0[n * 192 + o2] = a2;
  }
  __threadfence(); grid.sync(); __threadfence();

#pragma unroll
  for (int l = 0; l < 4; ++l) {
    const float* zc = (l == 0) ? h0 : ((l == 1) ? zA : ((l == 2) ? zB : zA));
    float* zo = (l & 1) ? zB : zA;
    float* ho = (l & 1) ? hB : hA;
    const float* hp = (l == 2) ? hB : hA;  // residual source, valid for l>=1
    // ---- PY: Y = zc @ B_l  (96 blocks: 16 row-blocks x 6 col-blocks) ----
    if (b < 96) {
      int rb = b / 6, cb = b % 6;
      int e0 = rb * 64;
      const _Float16* Bt = Btl + (size_t)l * 221184;
      {
        const char* g = (const char*)Bt + (((size_t)w * 1152 + cb * 192) * 8) * 2;
        char* lb = (char*)Bl + w * 3072;
#pragma unroll
        for (int r = 0; r < 3; ++r) gll16(g + r * 1024 + lane * 16, lb + r * 1024 + lane * 16);
      }
#pragma unroll
      for (int it = 0; it < 6; ++it) {
        int u = it * 256 + t;
        int row = u / 24, ck = u - row * 24;
        const float* ap = zc + (size_t)(e0 + row) * 192 + ck * 8;
        float4 v0 = *(const float4*)ap;
        float4 v1 = *(const float4*)(ap + 4);
        union { _Float16 h[8]; uint4 v; } uu;
        uu.h[0] = (_Float16)v0.x; uu.h[1] = (_Float16)v0.y;
        uu.h[2] = (_Float16)v0.z; uu.h[3] = (_Float16)v0.w;
        uu.h[4] = (_Float16)v1.x; uu.h[5] = (_Float16)v1.y;
        uu.h[6] = (_Float16)v1.z; uu.h[7] = (_Float16)v1.w;
        *(uint4*)(Al + ((size_t)ck * 64 + row) * 8) = uu.v;
      }
      __syncthreads();
      f32x4 acc[12] = {};
      int buf = 0;
      for (int ks = 0; ks < 6; ++ks) {
        if (ks < 5) {
          const char* g = (const char*)Bt + (((size_t)((ks + 1) * 4 + w) * 1152 + cb * 192) * 8) * 2;
          char* lb = (char*)Bl + (buf ^ 1) * 12288 + w * 3072;
#pragma unroll
          for (int r = 0; r < 3; ++r) gll16(g + r * 1024 + lane * 16, lb + r * 1024 + lane * 16);
        }
        half8 av = *(const half8*)(Al + (((ks * 4 + q4) * 64) + w * 16 + l15) * 8);
#pragma unroll
        for (int nt = 0; nt < 12; ++nt) {
          half8 bv = *(const half8*)(Bl + (size_t)buf * 6144 + ((q4 * 192) + nt * 16 + l15) * 8);
          acc[nt] = __builtin_amdgcn_mfma_f32_16x16x32_f16(av, bv, acc[nt], 0, 0, 0);
        }
        __syncthreads();
        buf ^= 1;
      }
#pragma unroll
      for (int nt = 0; nt < 12; ++nt) {
        int col = cb * 192 + nt * 16 + l15;
#pragma unroll
        for (int r = 0; r < 4; ++r) {
          int row = e0 + w * 16 + q4 * 4 + r;
          Y[(size_t)row * 1152 + col] = acc[nt][r];
        }
      }
    }
    __threadfence(); grid.sync(); __threadfence();
    // ---- PGN: gather by dst (CSR) + root + bias + residual + LN + relu ----
    {
      float v0 = 0.f, v1 = 0.f, v2 = 0.f;
      int beg = rowptr[n], end = rowptr[n + 1];
      for (int idx = beg; idx < end; ++idx) {
        int e = eord[idx];
        int s = ei[e];
        float4 u = ((const float4*)eattr)[e];
        const float* yr = Y + (size_t)s * 1152;
        v0 += yr[o0] * u.x + yr[192 + o0] * u.y + yr[384 + o0] * u.z + yr[576 + o0] * u.w + yr[768 + o0];
        v1 += yr[o1] * u.x + yr[192 + o1] * u.y + yr[384 + o1] * u.z + yr[576 + o1] * u.w + yr[768 + o1];
        v2 += yr[o2] * u.x + yr[192 + o2] * u.y + yr[384 + o2] * u.z + yr[576 + o2] * u.w + yr[768 + o2];
      }
      const float* yn = Y + (size_t)n * 1152 + 960;
      const float* cbv = conv_b + l * 192;
      v0 += yn[o0] + cbv[o0]; v1 += yn[o1] + cbv[o1]; v2 += yn[o2] + cbv[o2];
      if (l > 0) {
        v0 += hp[n * 192 + o0]; v1 += hp[n * 192 + o1]; v2 += hp[n * 192 + o2];
      }
      ho[n * 192 + o0] = v0; ho[n * 192 + o1] = v1; ho[n * 192 + o2] = v2;
      float s1 = v0 + v1 + v2, s2 = v0 * v0 + v1 * v1 + v2 * v2;
#pragma unroll
      for (int off = 32; off >= 1; off >>= 1) {
        s1 += __shfl_xor(s1, off);
        s2 += __shfl_xor(s2, off);
      }
      float mu = s1 * (1.f / 192.f);
      float var = s2 * (1.f / 192.f) - mu * mu;
      float rcp = rsqrtf(var + 1e-5f);
      int gi = (l == 3) ? 0 : (l + 1);
      const float* gg = ln_g + gi * 192;
      const float* bb = ln_b + gi * 192;
      zo[n * 192 + o0] = fmaxf((v0 - mu) * rcp * gg[o0] + bb[o0], 0.f);
      zo[n * 192 + o1] = fmaxf((v1 - mu) * rcp * gg[o1] + bb[o1], 0.f);
      zo[n * 192 + o2] = fmaxf((v2 - mu) * rcp * gg[o2] + bb[o2], 0.f);
    }
    __threadfence(); grid.sync(); __threadfence();
  }
  // ---- final linear (wave-per-node, z = zB after layer 3) ----
  {
    const float* zp = zB + (size_t)n * 192;
    float a0 = 0.f, a1 = 0.f;
#pragma unroll
    for (int j = 0; j < 3; ++j) {
      int k = lane + j * 64;
      float zk = zp[k];
      a0 += zk * out_w[k * 2];
      a1 += zk * out_w[k * 2 + 1];
    }
#pragma unroll
    for (int off = 32; off >= 1; off >>= 1) {
      a0 += __shfl_xor(a0, off);
      a1 += __shfl_xor(a1, off);
    }
    if (lane == 0) {
      outp[n * 2] = a0 + out_b[0];
      outp[n * 2 + 1] = a1 + out_b[1];
    }
  }
}

// ---------------- launch ----------------
extern "C" void kernel_launch(void* const* d_in, const int* in_sizes, int n_in,
                              void* d_out, int out_size, void* d_ws, size_t ws_size,
                              hipStream_t stream) {
  const float* x      = (const float*)d_in[0];
  const int*   ei     = (const int*)  d_in[1];
  const float* eattr  = (const float*)d_in[2];
  const float* cheb_w = (const float*)d_in[4];
  const float* cheb_b = (const float*)d_in[5];
  const float* eenc_w = (const float*)d_in[6];
  const float* eenc_b = (const float*)d_in[7];
  const float* nn1_w  = (const float*)d_in[8];
  const float* nn1_b  = (const float*)d_in[9];
  const float* nn2_w  = (const float*)d_in[10];
  const float* nn2_b  = (const float*)d_in[11];
  const float* root_w = (const float*)d_in[12];
  const float* conv_b = (const float*)d_in[13];
  const float* ln_g   = (const float*)d_in[14];
  const float* ln_bb  = (const float*)d_in[15];
  const float* out_w  = (const float*)d_in[16];
  const float* out_b  = (const float*)d_in[17];
  float* outp = (float*)d_out;
  (void)in_sizes; (void)n_in; (void)out_size; (void)ws_size;

  char* p = (char*)d_ws;
  _Float16* Btl = (_Float16*)p; p += (size_t)4 * 221184 * 2;       // 1.77 MB
  float* Ppart  = (float*)p;    p += (size_t)2 * 4 * 5 * 36864 * 4; // 5.9 MB
  float* Mbuf   = (float*)p;    p += 4 * 5 * 192 * 4;
  float* Tx     = (float*)p;    p += 5 * 4096 * 4;
  float* Y      = (float*)p;    p += (size_t)1024 * 1152 * 4;      // 4.7 MB
  float* h0     = (float*)p;    p += 196608 * 4;
  float* hA     = (float*)p;    p += 196608 * 4;
  float* hB     = (float*)p;    p += 196608 * 4;
  float* zA     = (float*)p;    p += 196608 * 4;
  float* zB     = (float*)p;    p += 196608 * 4;
  int* rowptr   = (int*)p;      p += 1056 * 4;                     // 1025 used
  int* eord     = (int*)p;      p += 2048 * 4;

  k_M<<<4, 256, 0, stream>>>(eenc_w, eenc_b, nn1_w, nn1_b, Mbuf);
  k_pb<<<dim3(37, 4, 2), 256, 0, stream>>>(nn2_w, Mbuf, Ppart, x, ei, Tx, rowptr, eord);

  const float* a_Pp = Ppart; const float* a_n2b = nn2_b; const float* a_rw = root_w;
  _Float16* a_Btl = Btl; const float* a_Tx = Tx; const float* a_cw = cheb_w;
  const float* a_cb = cheb_b; float* a_h0 = h0; const int* a_ei = ei;
  const float* a_ea = eattr; const int* a_rp = rowptr; const int* a_eo = eord;
  const float* a_cvb = conv_b; const float* a_lg = ln_g; const float* a_lb = ln_bb;
  const float* a_ow = out_w; const float* a_ob = out_b; float* a_Y = Y;
  float* a_hA = hA; float* a_hB = hB; float* a_zA = zA; float* a_zB = zB;
  float* a_out = outp;
  void* kargs[] = {
    (void*)&a_Pp, (void*)&a_n2b, (void*)&a_rw, (void*)&a_Btl, (void*)&a_Tx,
    (void*)&a_cw, (void*)&a_cb, (void*)&a_h0, (void*)&a_ei, (void*)&a_ea,
    (void*)&a_rp, (void*)&a_eo, (void*)&a_cvb, (void*)&a_lg, (void*)&a_lb,
    (void*)&a_ow, (void*)&a_ob, (void*)&a_Y, (void*)&a_hA, (void*)&a_hB,
    (void*)&a_zA, (void*)&a_zB, (void*)&a_out
  };
  hipLaunchCooperativeKernel((const void*)k_all, dim3(256, 1, 1), dim3(256, 1, 1),
                             kargs, 0u, stream);
}

// Round 2
// 296.057 us; speedup vs baseline: 3.3826x; 3.3826x over previous
//
#include <hip/hip_runtime.h>
#include <stdint.h>

typedef _Float16 half8 __attribute__((ext_vector_type(8)));
typedef float f32x4 __attribute__((ext_vector_type(4)));

// ---------------- P = M @ W2 (113MB stream, M computed in-block) + Cheb chain + CSR build ----------------
// grid (37,4,2): x<36 -> pb workers; (36,0,0) -> Cheb chain; (36,1,0) -> CSR by dst; rest exit.
__global__ __launch_bounds__(256)
void k_pb(const float* __restrict__ nn2_w, const float* __restrict__ eenc_w,
          const float* __restrict__ eenc_b, const float* __restrict__ nn1_w,
          const float* __restrict__ nn1_b, float* __restrict__ Ppart,
          const float* __restrict__ x, const int* __restrict__ ei,
          float* __restrict__ Tx, int* __restrict__ rowptr, int* __restrict__ eord) {
  __shared__ __align__(16) float smem[15360];  // 60KB, unioned across roles
  int t = threadIdx.x;
  if (blockIdx.x == 36) {
    if (blockIdx.y == 0 && blockIdx.z == 0) {
      // ---- Chebyshev chain (hides under the pb stream) ----
      float* deg = smem;            // 1024
      float* wn  = smem + 1024;     // 2048
      float* T0  = smem + 3072;     // 4096
      float* T1  = smem + 7168;     // 4096
      float* yv  = smem + 11264;    // 4096
      for (int i = t; i < 1024; i += 256) deg[i] = 0.f;
      __syncthreads();
      for (int e = t; e < 2048; e += 256) atomicAdd(&deg[ei[e]], 1.f);
      __syncthreads();
      for (int e = t; e < 2048; e += 256) {
        int s = ei[e], d = ei[2048 + e];
        float ds = deg[s], dd = deg[d];
        float a = ds > 0.f ? 1.f / sqrtf(fmaxf(ds, 1.f)) : 0.f;
        float b = dd > 0.f ? 1.f / sqrtf(fmaxf(dd, 1.f)) : 0.f;
        wn[e] = -a * b;
      }
      for (int i = t; i < 1024; i += 256) {
        float4 xv = ((const float4*)x)[i];
        ((float4*)T0)[i] = xv;
        ((float4*)Tx)[i] = xv;
      }
      __syncthreads();
      float* cur = T0; float* nxt = T1;
      for (int rec = 0; rec < 4; ++rec) {
        for (int i = t; i < 1024; i += 256) ((float4*)yv)[i] = make_float4(0.f, 0.f, 0.f, 0.f);
        __syncthreads();
        for (int e = t; e < 2048; e += 256) {
          int s = ei[e], d = ei[2048 + e];
          float wv = wn[e];
#pragma unroll
          for (int c = 0; c < 4; ++c) atomicAdd(&yv[d * 4 + c], wv * cur[s * 4 + c]);
        }
        __syncthreads();
        float a = (rec == 0) ? 1.f : 2.f;
        for (int i = t; i < 1024; i += 256) {
          float4 y4 = ((float4*)yv)[i];
          float4 p4 = ((float4*)nxt)[i];
          float4 n4;
          n4.x = a * y4.x - (rec ? p4.x : 0.f);
          n4.y = a * y4.y - (rec ? p4.y : 0.f);
          n4.z = a * y4.z - (rec ? p4.z : 0.f);
          n4.w = a * y4.w - (rec ? p4.w : 0.f);
          ((float4*)nxt)[i] = n4;
          ((float4*)(Tx + (rec + 1) * 4096))[i] = n4;
        }
        __syncthreads();
        float* tmp = cur; cur = nxt; nxt = tmp;
      }
    } else if (blockIdx.y == 1 && blockIdx.z == 0) {
      // ---- CSR by dst: rowptr[1025], eord[2048] ----
      int* cnt = (int*)smem;
      int* rp  = (int*)(smem + 1024);
      int* wtot = (int*)(smem + 2048);
      int lane = t & 63, wv = t >> 6;
      for (int i = t; i < 1024; i += 256) cnt[i] = 0;
      __syncthreads();
      for (int e = t; e < 2048; e += 256) atomicAdd(&cnt[ei[2048 + e]], 1);
      __syncthreads();
      int c0 = cnt[t * 4], c1 = cnt[t * 4 + 1], c2 = cnt[t * 4 + 2], c3 = cnt[t * 4 + 3];
      int s = c0 + c1 + c2 + c3;
      int inc = s;
#pragma unroll
      for (int off = 1; off < 64; off <<= 1) {
        int u = __shfl_up(inc, off);
        if (lane >= off) inc += u;
      }
      if (lane == 63) wtot[wv] = inc;
      __syncthreads();
      int woff = 0;
#pragma unroll
      for (int j = 0; j < 4; ++j) if (j < wv) woff += wtot[j];
      int excl = woff + inc - s;
      int4 r4; r4.x = excl; r4.y = excl + c0; r4.z = excl + c0 + c1; r4.w = excl + c0 + c1 + c2;
      *(int4*)(rowptr + t * 4) = r4;
      if (t == 0) rowptr[1024] = 2048;
      rp[t * 4] = r4.x; rp[t * 4 + 1] = r4.y; rp[t * 4 + 2] = r4.z; rp[t * 4 + 3] = r4.w;
      __syncthreads();
      for (int e = t; e < 2048; e += 256) {
        int d = ei[2048 + e];
        int slot = atomicAdd(&rp[d], 1);
        eord[slot] = e;
      }
    }
    return;
  }
  // ---- pb worker: compute M[l] in LDS, then k-split partials of P = M @ W2 ----
  int l = blockIdx.y, kc = blockIdx.z;
  if (t < 192) {
    float a0 = 0.f, a1 = 0.f, a2 = 0.f, a3 = 0.f, a4 = 0.f;
    const float* nw = nn1_w + (size_t)l * 36864 + t;
    for (int k = 0; k < 192; ++k) {
      float nv = nw[(size_t)k * 192];
      a0 += eenc_w[k] * nv;
      a1 += eenc_w[192 + k] * nv;
      a2 += eenc_w[384 + k] * nv;
      a3 += eenc_w[576 + k] * nv;
      a4 += eenc_b[k] * nv;
    }
    smem[t] = a0; smem[192 + t] = a1; smem[384 + t] = a2; smem[576 + t] = a3;
    smem[768 + t] = a4 + nn1_b[l * 192 + t];
  }
  __syncthreads();
  int col = blockIdx.x * 1024 + t * 4;
  const float* W = nn2_w + (size_t)l * 7077888 + col;
  const float* Mp = smem + kc * 96;
  f32x4 acc0 = {}, acc1 = {}, acc2 = {}, acc3 = {}, acc4 = {};
  const size_t rs = 36864;
  const float* Wk = W + (size_t)(kc * 96) * rs;
#pragma unroll 8
  for (int k = 0; k < 96; ++k) {
    f32x4 wv = *(const f32x4*)(Wk + (size_t)k * rs);
    acc0 += wv * Mp[k];
    acc1 += wv * Mp[192 + k];
    acc2 += wv * Mp[384 + k];
    acc3 += wv * Mp[576 + k];
    acc4 += wv * Mp[768 + k];
  }
  float* Pp = Ppart + ((size_t)(kc * 4 + l) * 5) * 36864 + col;
  *(f32x4*)(Pp) = acc0;
  *(f32x4*)(Pp + 36864) = acc1;
  *(f32x4*)(Pp + 2 * 36864) = acc2;
  *(f32x4*)(Pp + 3 * 36864) = acc3;
  *(f32x4*)(Pp + 4 * 36864) = acc4;
}

// ---------------- stage B f16 chunk-major (y<4) + cheb_out -> z0 f16 chunk-major (y==4) ----------------
__global__ __launch_bounds__(256)
void k_stage(const float* __restrict__ Ppart, const float* __restrict__ nn2_b,
             const float* __restrict__ root_w, _Float16* __restrict__ Btl,
             const float* __restrict__ Tx, const float* __restrict__ cheb_w,
             const float* __restrict__ cheb_b, _Float16* __restrict__ z0) {
  int t = threadIdx.x;
  if (blockIdx.y < 4) {
    int ck = blockIdx.x, l = blockIdx.y;
    _Float16* out = Btl + (size_t)l * 221184 + ck * 9216;
#pragma unroll
    for (int it = 0; it < 5; ++it) {
      int n = it * 256 + t;
      if (n >= 1152) break;
      union { _Float16 h[8]; uint4 v; } u;
      if (n < 960) {
        int c = n / 192, o = n - c * 192;
        const float* P0 = Ppart + ((size_t)(0 * 4 + l) * 5 + c) * 36864;
        const float* P1 = Ppart + ((size_t)(1 * 4 + l) * 5 + c) * 36864;
#pragma unroll
        for (int j = 0; j < 8; ++j) {
          int io = (ck * 8 + j) * 192 + o;
          float val = P0[io] + P1[io];
          if (c == 4) val += nn2_b[(size_t)l * 36864 + io];
          u.h[j] = (_Float16)val;
        }
      } else {
        int o = n - 960;
#pragma unroll
        for (int j = 0; j < 8; ++j)
          u.h[j] = (_Float16)root_w[(size_t)l * 36864 + (ck * 8 + j) * 192 + o];
      }
      *(uint4*)(out + (size_t)n * 8) = u.v;
    }
  } else {
    // cheb_out: z0[(ck*1024+n)*8+j] = f16( cheb_b[o] + sum Tx[k][n][c]*cheb_w[k*4+c][o] ), o=ck*8+j
    for (int i = blockIdx.x * 256 + t; i < 24576; i += 6144) {
      int n = i & 1023, ck = i >> 10;
      float tv[5][4];
#pragma unroll
      for (int k = 0; k < 5; ++k) {
        float4 t4 = ((const float4*)(Tx + k * 4096))[n];
        tv[k][0] = t4.x; tv[k][1] = t4.y; tv[k][2] = t4.z; tv[k][3] = t4.w;
      }
      union { _Float16 h[8]; uint4 v; } u;
#pragma unroll
      for (int j = 0; j < 8; ++j) {
        int o = ck * 8 + j;
        float acc = cheb_b[o];
#pragma unroll
        for (int k = 0; k < 5; ++k)
#pragma unroll
          for (int c = 0; c < 4; ++c)
            acc += tv[k][c] * cheb_w[(k * 4 + c) * 192 + o];
        u.h[j] = (_Float16)acc;
      }
      *(uint4*)(z0 + ((size_t)ck * 1024 + n) * 8) = u.v;
    }
  }
}

// ---------------- Y = z16 @ B  (1024 x 1152, K=192), fragments straight from global ----------------
__global__ __launch_bounds__(256)
void k_y(const _Float16* __restrict__ z16, const _Float16* __restrict__ Btl,
         float* __restrict__ Y, int layer) {
  int t = threadIdx.x;
  int w = t >> 6, lane = t & 63, l15 = lane & 15, q4 = lane >> 4;
  int e0 = blockIdx.x * 64, cb = blockIdx.y;
  const _Float16* Bt = Btl + (size_t)layer * 221184;
  const _Float16* ap = z16 + (((size_t)q4 * 1024) + e0 + w * 16 + l15) * 8;
  const _Float16* bp = Bt + (((size_t)q4 * 1152) + cb * 192 + l15) * 8;
  f32x4 acc[12] = {};
#pragma unroll
  for (int ks = 0; ks < 6; ++ks) {
    half8 av = *(const half8*)(ap + (size_t)ks * 4 * 1024 * 8);
#pragma unroll
    for (int nt = 0; nt < 12; ++nt) {
      half8 bv = *(const half8*)(bp + (size_t)ks * 4 * 1152 * 8 + nt * 16 * 8);
      acc[nt] = __builtin_amdgcn_mfma_f32_16x16x32_f16(av, bv, acc[nt], 0, 0, 0);
    }
  }
#pragma unroll
  for (int nt = 0; nt < 12; ++nt) {
    int col = cb * 192 + nt * 16 + l15;
#pragma unroll
    for (int r = 0; r < 4; ++r) {
      int row = e0 + w * 16 + q4 * 4 + r;
      Y[(size_t)row * 1152 + col] = acc[nt][r];
    }
  }
}

// ---------------- gather by dst (CSR) + root + bias + residual + LN + relu (+ final for l==3) ----------------
__global__ __launch_bounds__(256)
void k_gn(const int* __restrict__ ei, const float* __restrict__ eattr,
          const int* __restrict__ rowptr, const int* __restrict__ eord,
          const float* __restrict__ Y, const float* __restrict__ hp,
          const float* __restrict__ cbv, const float* __restrict__ gg,
          const float* __restrict__ bb, float* __restrict__ ho,
          _Float16* __restrict__ zo, const float* __restrict__ out_w,
          const float* __restrict__ out_b, float* __restrict__ outp, int l) {
  int t = threadIdx.x, w = t >> 6, lane = t & 63;
  int n = blockIdx.x * 4 + w;
  int o0 = lane, o1 = lane + 64, o2 = lane + 128;
  float v0 = 0.f, v1 = 0.f, v2 = 0.f;
  int beg = rowptr[n], end = rowptr[n + 1];
  for (int idx = beg; idx < end; ++idx) {
    int e = eord[idx];
    int s = ei[e];
    float4 u = ((const float4*)eattr)[e];
    const float* yr = Y + (size_t)s * 1152;
    v0 += yr[o0] * u.x + yr[192 + o0] * u.y + yr[384 + o0] * u.z + yr[576 + o0] * u.w + yr[768 + o0];
    v1 += yr[o1] * u.x + yr[192 + o1] * u.y + yr[384 + o1] * u.z + yr[576 + o1] * u.w + yr[768 + o1];
    v2 += yr[o2] * u.x + yr[192 + o2] * u.y + yr[384 + o2] * u.z + yr[576 + o2] * u.w + yr[768 + o2];
  }
  const float* yn = Y + (size_t)n * 1152 + 960;
  v0 += yn[o0] + cbv[o0]; v1 += yn[o1] + cbv[o1]; v2 += yn[o2] + cbv[o2];
  if (l > 0) {
    v0 += hp[n * 192 + o0]; v1 += hp[n * 192 + o1]; v2 += hp[n * 192 + o2];
  }
  if (l < 3) {
    ho[n * 192 + o0] = v0; ho[n * 192 + o1] = v1; ho[n * 192 + o2] = v2;
  }
  float s1 = v0 + v1 + v2, s2 = v0 * v0 + v1 * v1 + v2 * v2;
#pragma unroll
  for (int off = 32; off >= 1; off >>= 1) {
    s1 += __shfl_xor(s1, off);
    s2 += __shfl_xor(s2, off);
  }
  float mu = s1 * (1.f / 192.f);
  float var = s2 * (1.f / 192.f) - mu * mu;
  float rcp = rsqrtf(var + 1e-5f);
  float z0v = fmaxf((v0 - mu) * rcp * gg[o0] + bb[o0], 0.f);
  float z1v = fmaxf((v1 - mu) * rcp * gg[o1] + bb[o1], 0.f);
  float z2v = fmaxf((v2 - mu) * rcp * gg[o2] + bb[o2], 0.f);
  if (l < 3) {
    zo[((size_t)(o0 >> 3) * 1024 + n) * 8 + (o0 & 7)] = (_Float16)z0v;
    zo[((size_t)(o1 >> 3) * 1024 + n) * 8 + (o1 & 7)] = (_Float16)z1v;
    zo[((size_t)(o2 >> 3) * 1024 + n) * 8 + (o2 & 7)] = (_Float16)z2v;
  } else {
    float a0 = z0v * out_w[o0 * 2] + z1v * out_w[o1 * 2] + z2v * out_w[o2 * 2];
    float a1 = z0v * out_w[o0 * 2 + 1] + z1v * out_w[o1 * 2 + 1] + z2v * out_w[o2 * 2 + 1];
#pragma unroll
    for (int off = 32; off >= 1; off >>= 1) {
      a0 += __shfl_xor(a0, off);
      a1 += __shfl_xor(a1, off);
    }
    if (lane == 0) {
      outp[n * 2] = a0 + out_b[0];
      outp[n * 2 + 1] = a1 + out_b[1];
    }
  }
}

// ---------------- launch ----------------
extern "C" void kernel_launch(void* const* d_in, const int* in_sizes, int n_in,
                              void* d_out, int out_size, void* d_ws, size_t ws_size,
                              hipStream_t stream) {
  const float* x      = (const float*)d_in[0];
  const int*   ei     = (const int*)  d_in[1];
  const float* eattr  = (const float*)d_in[2];
  const float* cheb_w = (const float*)d_in[4];
  const float* cheb_b = (const float*)d_in[5];
  const float* eenc_w = (const float*)d_in[6];
  const float* eenc_b = (const float*)d_in[7];
  const float* nn1_w  = (const float*)d_in[8];
  const float* nn1_b  = (const float*)d_in[9];
  const float* nn2_w  = (const float*)d_in[10];
  const float* nn2_b  = (const float*)d_in[11];
  const float* root_w = (const float*)d_in[12];
  const float* conv_b = (const float*)d_in[13];
  const float* ln_g   = (const float*)d_in[14];
  const float* ln_bb  = (const float*)d_in[15];
  const float* out_w  = (const float*)d_in[16];
  const float* out_b  = (const float*)d_in[17];
  float* outp = (float*)d_out;
  (void)in_sizes; (void)n_in; (void)out_size; (void)ws_size;

  char* p = (char*)d_ws;
  _Float16* Btl = (_Float16*)p; p += (size_t)4 * 221184 * 2;        // 1.77 MB
  float* Ppart  = (float*)p;    p += (size_t)2 * 4 * 5 * 36864 * 4; // 5.9 MB
  float* Tx     = (float*)p;    p += 5 * 4096 * 4;
  float* Y      = (float*)p;    p += (size_t)1024 * 1152 * 4;       // 4.7 MB
  float* hA     = (float*)p;    p += 196608 * 4;
  float* hB     = (float*)p;    p += 196608 * 4;
  _Float16* z0  = (_Float16*)p; p += 196608 * 2;
  _Float16* zA  = (_Float16*)p; p += 196608 * 2;
  _Float16* zB  = (_Float16*)p; p += 196608 * 2;
  int* rowptr   = (int*)p;      p += 1056 * 4;
  int* eord     = (int*)p;      p += 2048 * 4;

  k_pb<<<dim3(37, 4, 2), 256, 0, stream>>>(nn2_w, eenc_w, eenc_b, nn1_w, nn1_b,
                                           Ppart, x, ei, Tx, rowptr, eord);
  k_stage<<<dim3(24, 5), 256, 0, stream>>>(Ppart, nn2_b, root_w, Btl, Tx,
                                           cheb_w, cheb_b, z0);

  const _Float16* zin[4] = {z0, zA, zB, zA};
  _Float16* zout[4] = {zA, zB, zA, zA};       // zout[3] unused
  float* hout[4] = {hA, hB, hA, hA};          // hout[3] unused
  const float* hres[4] = {hA, hA, hB, hA};    // hres[0] unused
  for (int l = 0; l < 4; ++l) {
    k_y<<<dim3(16, 6), 256, 0, stream>>>(zin[l], Btl, Y, l);
    k_gn<<<256, 256, 0, stream>>>(ei, eattr, rowptr, eord, Y, hres[l],
                                  conv_b + (size_t)l * 192,
                                  ln_g + (size_t)((l == 3) ? 0 : (l + 1)) * 192,
                                  ln_bb + (size_t)((l == 3) ? 0 : (l + 1)) * 192,
                                  hout[l], zout[l], out_w, out_b, outp, l);
  }
}